// Round 1
// baseline (1141.242 us; speedup 1.0000x reference)
//
#include <hip/hip_runtime.h>
#include <math.h>

#define BATCH  2
#define CH     128
#define SP     65536            // D*H*W
#define NPOS   (BATCH*SP)       // 131072
#define GROUPS 32
#define GSIZE  (4*SP)           // elems per (b,group) = 262144
#define HEADS  4
#define DHD    32
#define NMEM   4
#define EPSV   1e-5f
#define SCALE  0.17677669529663687f   // 32^-0.5

// ---------------- group-norm partial stats (2048 blocks x 8192 elems) ----------------
__global__ __launch_bounds__(256) void gn_partial(const float* __restrict__ x,
                                                  float* __restrict__ part) {
    __shared__ float s1[256], s2[256];
    int t = threadIdx.x;
    const float4* xp = (const float4*)(x + (size_t)blockIdx.x * 8192);
    float s = 0.f, q = 0.f;
#pragma unroll
    for (int i = 0; i < 8; ++i) {
        float4 v = xp[t + 256 * i];
        s += v.x + v.y + v.z + v.w;
        q += v.x * v.x + v.y * v.y + v.z * v.z + v.w * v.w;
    }
    s1[t] = s; s2[t] = q;
    __syncthreads();
    for (int st = 128; st > 0; st >>= 1) {
        if (t < st) { s1[t] += s1[t + st]; s2[t] += s2[t + st]; }
        __syncthreads();
    }
    if (t == 0) { part[2 * blockIdx.x] = s1[0]; part[2 * blockIdx.x + 1] = s2[0]; }
}

// ---------------- finalize gn1 stats + init ctx/Z with memory-kv contributions --------
__global__ __launch_bounds__(256) void prep(const float* __restrict__ part,
                                            const float* __restrict__ mem_kv,
                                            float* __restrict__ mu, float* __restrict__ rs,
                                            float* __restrict__ ctx, float* __restrict__ Z) {
    int t = threadIdx.x;
    if (t < 64) {
        float s = 0.f, q = 0.f;
        for (int i = 0; i < 32; ++i) { s += part[2*(t*32+i)]; q += part[2*(t*32+i)+1]; }
        float m = s * (1.f / (float)GSIZE);
        float v = q * (1.f / (float)GSIZE) - m * m;
        mu[t] = m; rs[t] = rsqrtf(v + EPSV);
    }
    {   // Z init: exp of memory-k slots.  t = b*128 + h*32 + d  (mem shared across b)
        int d = t & 31, h = (t >> 5) & 3;
        float z = 0.f;
        for (int m2 = 0; m2 < NMEM; ++m2) z += expf(mem_kv[(h*32+d)*4 + m2]);
        Z[t] = z;
    }
    // ctx init: sum_m exp(mk[h,d,m]) * mv[h,e,m].   idx = b*4096 + h*1024 + d*32 + e
    for (int idx = t; idx < 8192; idx += 256) {
        int e = idx & 31, d = (idx >> 5) & 31, h = (idx >> 10) & 3;
        float c = 0.f;
        for (int m2 = 0; m2 < NMEM; ++m2)
            c += expf(mem_kv[(h*32+d)*4 + m2]) * mem_kv[512 + (h*32+e)*4 + m2];
        ctx[idx] = c;
    }
}

// ---------------- k/v pass: accumulate ctx[d,e] += exp(k_d)*v_e , Z[d] += exp(k_d) ----
__global__ __launch_bounds__(256) void kv_pass(const float* __restrict__ x,
        const float* __restrict__ w_qkv,
        const float* __restrict__ n1w, const float* __restrict__ n1b,
        const float* __restrict__ mu, const float* __restrict__ rs,
        float* __restrict__ ctx, float* __restrict__ Z) {
    __shared__ union {
        struct { float xns[128][64]; float wsm[256][17]; } a;
        float kvs[256][66];           // rows 0..127 = exp(k), 128..255 = v  (padded: col reads)
    } sm;
    int tid = threadIdx.x;
    int p0 = blockIdx.x << 6;
    int b  = p0 >> 16;
    int n0 = p0 & 65535;

    // load + normalize x tile (128 ch x 64 pos)
#pragma unroll
    for (int it = 0; it < 8; ++it) {
        int fi = it * 256 + tid;
        int c = fi >> 4, nq = fi & 15;
        float4 v = *(const float4*)(x + ((b*CH + c) << 16) + n0 + nq*4);
        int fg = b*32 + (c >> 2);
        float aa = rs[fg] * n1w[c];
        float bb = n1b[c] - mu[fg] * aa;
        sm.a.xns[c][nq*4+0] = v.x*aa+bb;
        sm.a.xns[c][nq*4+1] = v.y*aa+bb;
        sm.a.xns[c][nq*4+2] = v.z*aa+bb;
        sm.a.xns[c][nq*4+3] = v.w*aa+bb;
    }

    float acc[8][8];
#pragma unroll
    for (int i = 0; i < 8; ++i)
#pragma unroll
        for (int j = 0; j < 8; ++j) acc[i][j] = 0.f;

    int rt = tid >> 3, nt = tid & 7;         // 32 row-groups x 8 n-groups
    for (int cc = 0; cc < 128; cc += 16) {
        __syncthreads();
#pragma unroll
        for (int it = 0; it < 4; ++it) {     // w_qkv rows 128..383, 16-col chunk
            int fi = it * 256 + tid;         // 1024 float4
            int r = fi >> 2, cq = fi & 3;
            float4 v = *(const float4*)(w_qkv + (128 + r)*CH + cc + cq*4);
            sm.a.wsm[r][cq*4+0] = v.x;
            sm.a.wsm[r][cq*4+1] = v.y;
            sm.a.wsm[r][cq*4+2] = v.z;
            sm.a.wsm[r][cq*4+3] = v.w;
        }
        __syncthreads();
#pragma unroll
        for (int k = 0; k < 16; ++k) {
            float rw[8], xv[8];
#pragma unroll
            for (int i = 0; i < 8; ++i) rw[i] = sm.a.wsm[rt*8+i][k];
#pragma unroll
            for (int j = 0; j < 8; ++j) xv[j] = sm.a.xns[cc+k][nt*8+j];
#pragma unroll
            for (int i = 0; i < 8; ++i)
#pragma unroll
                for (int j = 0; j < 8; ++j) acc[i][j] += rw[i]*xv[j];
        }
    }
    __syncthreads();                          // all GEMM LDS reads done before union overwrite
#pragma unroll
    for (int i = 0; i < 8; ++i) {
        int row = rt*8 + i;
#pragma unroll
        for (int j = 0; j < 8; ++j)
            sm.kvs[row][nt*8+j] = (row < 128) ? expf(acc[i][j]) : acc[i][j];
    }
    __syncthreads();

    // block-local context: thread = (head h, d = l>>1, e-halfblock)
    int h = tid >> 6, l = tid & 63;
    int d = l >> 1, eb = (l & 1) * 16;
    float cacc[16];
#pragma unroll
    for (int i = 0; i < 16; ++i) cacc[i] = 0.f;
    float zacc = 0.f;
    for (int nn = 0; nn < 64; ++nn) {
        float ek = sm.kvs[h*32+d][nn];
        zacc += ek;
#pragma unroll
        for (int i = 0; i < 16; ++i)
            cacc[i] += ek * sm.kvs[128 + h*32 + eb + i][nn];
    }
    float* cb = ctx + b*4096 + h*1024 + d*32 + eb;
#pragma unroll
    for (int i = 0; i < 16; ++i) atomicAdd(cb + i, cacc[i]);
    if ((l & 1) == 0) atomicAdd(Z + b*128 + h*32 + d, zacc);
}

// ---------------- out pass: q GEMM -> softmax(d) -> ctx apply -> w_out GEMM -----------
__global__ __launch_bounds__(256) void out_pass(const float* __restrict__ x,
        const float* __restrict__ w_qkv,
        const float* __restrict__ n1w, const float* __restrict__ n1b,
        const float* __restrict__ mu, const float* __restrict__ rs,
        const float* __restrict__ ctx, const float* __restrict__ Z,
        const float* __restrict__ w_out, const float* __restrict__ b_out,
        float* __restrict__ out) {
    __shared__ union { float xns[128][64]; float hid[128][64]; } ra;
    __shared__ union { float wsm[128][17]; float ctxs[4][32][32]; } rb;
    __shared__ float qs[128][64];
    int tid = threadIdx.x;
    int p0 = blockIdx.x << 6;
    int b  = p0 >> 16;
    int n0 = p0 & 65535;

    // x tile
#pragma unroll
    for (int it = 0; it < 8; ++it) {
        int fi = it * 256 + tid;
        int c = fi >> 4, nq = fi & 15;
        float4 v = *(const float4*)(x + ((b*CH + c) << 16) + n0 + nq*4);
        int fg = b*32 + (c >> 2);
        float aa = rs[fg] * n1w[c];
        float bb = n1b[c] - mu[fg] * aa;
        ra.xns[c][nq*4+0] = v.x*aa+bb;
        ra.xns[c][nq*4+1] = v.y*aa+bb;
        ra.xns[c][nq*4+2] = v.z*aa+bb;
        ra.xns[c][nq*4+3] = v.w*aa+bb;
    }

    float acc[4][8];
#pragma unroll
    for (int i = 0; i < 4; ++i)
#pragma unroll
        for (int j = 0; j < 8; ++j) acc[i][j] = 0.f;
    int rt = tid >> 3, nt = tid & 7;
    for (int cc = 0; cc < 128; cc += 16) {    // q GEMM: w_qkv rows 0..127
        __syncthreads();
#pragma unroll
        for (int it = 0; it < 2; ++it) {
            int fi = it * 256 + tid;          // 512 float4
            int r = fi >> 2, cq = fi & 3;
            float4 v = *(const float4*)(w_qkv + r*CH + cc + cq*4);
            rb.wsm[r][cq*4+0] = v.x;
            rb.wsm[r][cq*4+1] = v.y;
            rb.wsm[r][cq*4+2] = v.z;
            rb.wsm[r][cq*4+3] = v.w;
        }
        __syncthreads();
#pragma unroll
        for (int k = 0; k < 16; ++k) {
            float rw[4], xv[8];
#pragma unroll
            for (int i = 0; i < 4; ++i) rw[i] = rb.wsm[rt*4+i][k];
#pragma unroll
            for (int j = 0; j < 8; ++j) xv[j] = ra.xns[cc+k][nt*8+j];
#pragma unroll
            for (int i = 0; i < 4; ++i)
#pragma unroll
                for (int j = 0; j < 8; ++j) acc[i][j] += rw[i]*xv[j];
        }
    }
    __syncthreads();                           // q-GEMM reads of wsm/xns complete
    // stage raw q
#pragma unroll
    for (int i = 0; i < 4; ++i)
#pragma unroll
        for (int j = 0; j < 8; ++j) qs[rt*4+i][nt*8+j] = acc[i][j];
    // load normalized context (wsm now dead)
    for (int idx = tid; idx < 4096; idx += 256) {
        int e = idx & 31, dd = (idx >> 5) & 31, h2 = idx >> 10;
        rb.ctxs[h2][dd][e] = ctx[b*4096 + idx] / Z[b*128 + h2*32 + dd];
    }
    __syncthreads();

    {   // softmax over d per (h,n) column; write back prob*scale
        int h2 = tid >> 6, n = tid & 63;
        float pv[32]; float ssum = 0.f;
#pragma unroll
        for (int dd = 0; dd < 32; ++dd) { pv[dd] = expf(qs[h2*32+dd][n]); ssum += pv[dd]; }
        float inv = SCALE / ssum;
#pragma unroll
        for (int dd = 0; dd < 32; ++dd) qs[h2*32+dd][n] = pv[dd] * inv;
    }
    __syncthreads();

    {   // hid[e][n] = sum_d ctx[d][e] * qprob[d][n]   (per head)
        int h2 = tid >> 6, l = tid & 63;
        int et = l >> 3, nt2 = l & 7;
        float a3[4][8];
#pragma unroll
        for (int i = 0; i < 4; ++i)
#pragma unroll
            for (int j = 0; j < 8; ++j) a3[i][j] = 0.f;
#pragma unroll
        for (int dd = 0; dd < 32; ++dd) {
            float4 cv = *(const float4*)&rb.ctxs[h2][dd][et*4];
            float rw[4] = {cv.x, cv.y, cv.z, cv.w};
            float xv[8];
#pragma unroll
            for (int j = 0; j < 8; ++j) xv[j] = qs[h2*32+dd][nt2*8+j];
#pragma unroll
            for (int i = 0; i < 4; ++i)
#pragma unroll
                for (int j = 0; j < 8; ++j) a3[i][j] += rw[i]*xv[j];
        }
#pragma unroll
        for (int i = 0; i < 4; ++i)
#pragma unroll
            for (int j = 0; j < 8; ++j) ra.hid[h2*32 + et*4 + i][nt2*8 + j] = a3[i][j];
    }

    float a2[4][8];
#pragma unroll
    for (int i = 0; i < 4; ++i)
#pragma unroll
        for (int j = 0; j < 8; ++j) a2[i][j] = 0.f;
    for (int cc = 0; cc < 128; cc += 16) {     // final GEMM: w_out @ hid
        __syncthreads();                        // ctxs reads / hid writes done before wsm reuse
#pragma unroll
        for (int it = 0; it < 2; ++it) {
            int fi = it * 256 + tid;
            int r = fi >> 2, cq = fi & 3;
            float4 v = *(const float4*)(w_out + r*CH + cc + cq*4);
            rb.wsm[r][cq*4+0] = v.x;
            rb.wsm[r][cq*4+1] = v.y;
            rb.wsm[r][cq*4+2] = v.z;
            rb.wsm[r][cq*4+3] = v.w;
        }
        __syncthreads();
#pragma unroll
        for (int k = 0; k < 16; ++k) {
            float rw[4], hv[8];
#pragma unroll
            for (int i = 0; i < 4; ++i) rw[i] = rb.wsm[rt*4+i][k];
#pragma unroll
            for (int j = 0; j < 8; ++j) hv[j] = ra.hid[cc+k][nt*8+j];
#pragma unroll
            for (int i = 0; i < 4; ++i)
#pragma unroll
                for (int j = 0; j < 8; ++j) a2[i][j] += rw[i]*hv[j];
        }
    }
#pragma unroll
    for (int i = 0; i < 4; ++i) {
        int c = rt*4 + i;
        float bo = b_out[c];
        float4 o0 = make_float4(a2[i][0]+bo, a2[i][1]+bo, a2[i][2]+bo, a2[i][3]+bo);
        float4 o1 = make_float4(a2[i][4]+bo, a2[i][5]+bo, a2[i][6]+bo, a2[i][7]+bo);
        float* dst = out + ((b*CH + c) << 16) + n0 + nt*8;
        *(float4*)dst = o0;
        *(float4*)(dst + 4) = o1;
    }
}

// ---------------- gn2 finalize + apply -------------------------------------------------
__global__ void reduce2(const float* __restrict__ part, float* __restrict__ mu, float* __restrict__ rs) {
    int t = threadIdx.x;
    if (t < 64) {
        float s = 0.f, q = 0.f;
        for (int i = 0; i < 32; ++i) { s += part[2*(t*32+i)]; q += part[2*(t*32+i)+1]; }
        float m = s * (1.f/(float)GSIZE);
        float v = q * (1.f/(float)GSIZE) - m*m;
        mu[t] = m; rs[t] = rsqrtf(v + EPSV);
    }
}

__global__ __launch_bounds__(256) void gn_apply(float* __restrict__ y,
        const float* __restrict__ mu, const float* __restrict__ rs,
        const float* __restrict__ w2, const float* __restrict__ b2) {
    int bi = blockIdx.x, t = threadIdx.x;
    int c = (bi >> 3) & 127;
    int b = bi >> 10;
    int fg = b*32 + (c >> 2);
    float aa = rs[fg] * w2[c];
    float bb = b2[c] - mu[fg] * aa;
    float4* yp = (float4*)(y + (size_t)bi * 8192);
#pragma unroll
    for (int i = 0; i < 8; ++i) {
        float4 v = yp[t + 256*i];
        v.x = v.x*aa+bb; v.y = v.y*aa+bb; v.z = v.z*aa+bb; v.w = v.w*aa+bb;
        yp[t + 256*i] = v;
    }
}

extern "C" void kernel_launch(void* const* d_in, const int* in_sizes, int n_in,
                              void* d_out, int out_size, void* d_ws, size_t ws_size,
                              hipStream_t stream) {
    (void)in_sizes; (void)n_in; (void)out_size; (void)ws_size;
    const float* x      = (const float*)d_in[0];
    const float* n1w    = (const float*)d_in[1];
    const float* n1b    = (const float*)d_in[2];
    const float* w_qkv  = (const float*)d_in[3];
    const float* mem_kv = (const float*)d_in[4];
    const float* w_out  = (const float*)d_in[5];
    const float* b_out  = (const float*)d_in[6];
    const float* n2w    = (const float*)d_in[7];
    const float* n2b    = (const float*)d_in[8];
    float* out = (float*)d_out;
    float* ws  = (float*)d_ws;

    float* part1 = ws;            // 4096
    float* mu1   = ws + 4096;     // 64
    float* rs1   = ws + 4160;     // 64
    float* ctx   = ws + 4224;     // 8192
    float* Z     = ws + 12416;    // 256
    float* part2 = ws + 12672;    // 4096
    float* mu2   = ws + 16768;    // 64
    float* rs2   = ws + 16832;    // 64   (total 16896 floats = 67.6 KB)

    gn_partial<<<2048, 256, 0, stream>>>(x, part1);
    prep<<<1, 256, 0, stream>>>(part1, mem_kv, mu1, rs1, ctx, Z);
    kv_pass<<<2048, 256, 0, stream>>>(x, w_qkv, n1w, n1b, mu1, rs1, ctx, Z);
    out_pass<<<2048, 256, 0, stream>>>(x, w_qkv, n1w, n1b, mu1, rs1, ctx, Z, w_out, b_out, out);
    gn_partial<<<2048, 256, 0, stream>>>(out, part2);
    reduce2<<<1, 64, 0, stream>>>(part2, mu2, rs2);
    gn_apply<<<2048, 256, 0, stream>>>(out, mu2, rs2, n2w, n2b);
}

// Round 2
// 599.299 us; speedup vs baseline: 1.9043x; 1.9043x over previous
//
#include <hip/hip_runtime.h>
#include <math.h>

#define CH     128
#define EPSV   1e-5f
#define SCALE  0.17677669529663687f   // 32^-0.5
#define GSIZE  262144.0f

// ---------------- group-norm partial stats (2048 blocks x 8192 elems) ----------------
__global__ __launch_bounds__(256) void gn_partial(const float* __restrict__ x,
                                                  float* __restrict__ part) {
    __shared__ float s1[256], s2[256];
    int t = threadIdx.x;
    const float4* xp = (const float4*)(x + (size_t)blockIdx.x * 8192);
    float s = 0.f, q = 0.f;
#pragma unroll
    for (int i = 0; i < 8; ++i) {
        float4 v = xp[t + 256 * i];
        s += v.x + v.y + v.z + v.w;
        q += v.x * v.x + v.y * v.y + v.z * v.z + v.w * v.w;
    }
    s1[t] = s; s2[t] = q;
    __syncthreads();
    for (int st = 128; st > 0; st >>= 1) {
        if (t < st) { s1[t] += s1[t + st]; s2[t] += s2[t + st]; }
        __syncthreads();
    }
    if (t == 0) { part[2 * blockIdx.x] = s1[0]; part[2 * blockIdx.x + 1] = s2[0]; }
}

// ---------------- finalize gn1 stats ---------------------------------------------------
__global__ void prep1(const float* __restrict__ part, float* __restrict__ mu, float* __restrict__ rs) {
    int t = threadIdx.x;   // 64 threads
    float s = 0.f, q = 0.f;
    for (int i = 0; i < 32; ++i) { s += part[2*(t*32+i)]; q += part[2*(t*32+i)+1]; }
    float m = s * (1.f / GSIZE);
    float v = q * (1.f / GSIZE) - m * m;
    mu[t] = m; rs[t] = rsqrtf(v + EPSV);
}

// ---------------- k/v pass: per-block partial ctx/Z, no atomics ------------------------
// grid 512; block bi handles tiles bi*4 .. bi*4+3 (64 positions each), all in batch bi>>8.
__global__ __launch_bounds__(256, 2) void kv_pass(const float* __restrict__ x,
        const float* __restrict__ w_qkv,
        const float* __restrict__ n1w, const float* __restrict__ n1b,
        const float* __restrict__ mu, const float* __restrict__ rs,
        float* __restrict__ part_kv) {
    __shared__ union {
        struct { float xns[128][68]; float wsmT[16][260]; } a;
        float kvs[17408];          // [256 rows][68], 4-float granules XOR-swizzled by (row>>3)&7
    } sm;
    int tid = threadIdx.x;
    int rt = tid >> 3, nt = tid & 7;                 // GEMM micro-tile coords
    int nnq = tid & 3, eh = (tid >> 2) & 1;          // ctx-phase coords
    int dq  = (tid >> 3) & 7, h = tid >> 6;

    float cacc[4][16];
    float zacc[4];
#pragma unroll
    for (int dd = 0; dd < 4; ++dd) {
        zacc[dd] = 0.f;
#pragma unroll
        for (int e = 0; e < 16; ++e) cacc[dd][e] = 0.f;
    }

    int b = blockIdx.x >> 8;

    for (int t4 = 0; t4 < 4; ++t4) {
        int n0 = ((blockIdx.x * 4 + t4) << 6) & 65535;

        // stage + normalize x tile (128 ch x 64 pos)
#pragma unroll
        for (int it = 0; it < 8; ++it) {
            int fi = it * 256 + tid;
            int c = fi >> 4, nq = fi & 15;
            float4 v = *(const float4*)(x + ((b*CH + c) << 16) + n0 + nq*4);
            int fg = b*32 + (c >> 2);
            float aa = rs[fg] * n1w[c];
            float bb = n1b[c] - mu[fg] * aa;
            *(float4*)&sm.a.xns[c][nq*4] =
                make_float4(v.x*aa+bb, v.y*aa+bb, v.z*aa+bb, v.w*aa+bb);
        }

        float acc[8][8];
#pragma unroll
        for (int i = 0; i < 8; ++i)
#pragma unroll
            for (int j = 0; j < 8; ++j) acc[i][j] = 0.f;

        for (int cc = 0; cc < 128; cc += 16) {
            __syncthreads();
#pragma unroll
            for (int it = 0; it < 4; ++it) {         // stage w_qkv rows 128..383, 16 cols, transposed
                int fi = it * 256 + tid;
                int r = fi >> 2, cq = fi & 3;
                float4 v = *(const float4*)(w_qkv + (128 + r)*CH + cc + cq*4);
                sm.a.wsmT[cq*4+0][r] = v.x;
                sm.a.wsmT[cq*4+1][r] = v.y;
                sm.a.wsmT[cq*4+2][r] = v.z;
                sm.a.wsmT[cq*4+3][r] = v.w;
            }
            __syncthreads();
#pragma unroll
            for (int k = 0; k < 16; ++k) {
                float4 w0 = *(float4*)&sm.a.wsmT[k][rt*8];
                float4 w1 = *(float4*)&sm.a.wsmT[k][rt*8+4];
                float4 x0 = *(float4*)&sm.a.xns[cc+k][nt*8];
                float4 x1 = *(float4*)&sm.a.xns[cc+k][nt*8+4];
                float rw[8] = {w0.x,w0.y,w0.z,w0.w,w1.x,w1.y,w1.z,w1.w};
                float xv[8] = {x0.x,x0.y,x0.z,x0.w,x1.x,x1.y,x1.z,x1.w};
#pragma unroll
                for (int i = 0; i < 8; ++i)
#pragma unroll
                    for (int j = 0; j < 8; ++j) acc[i][j] += rw[i]*xv[j];
            }
        }
        __syncthreads();                 // GEMM LDS reads done before union overwrite

        // write exp(k)/v into kvs (row-major, granule-swizzled)
        int sw = rt & 7;
#pragma unroll
        for (int i = 0; i < 8; ++i) {
            int row = rt*8 + i;
            float4 lo, hi;
            if (row < 128) {
                lo = make_float4(expf(acc[i][0]), expf(acc[i][1]), expf(acc[i][2]), expf(acc[i][3]));
                hi = make_float4(expf(acc[i][4]), expf(acc[i][5]), expf(acc[i][6]), expf(acc[i][7]));
            } else {
                lo = make_float4(acc[i][0], acc[i][1], acc[i][2], acc[i][3]);
                hi = make_float4(acc[i][4], acc[i][5], acc[i][6], acc[i][7]);
            }
            int g0 = (2*nt) ^ sw, g1 = (2*nt + 1) ^ sw;
            *(float4*)&sm.kvs[row*68 + g0*4] = lo;
            *(float4*)&sm.kvs[row*68 + g1*4] = hi;
        }
        __syncthreads();

        // ctx accumulate: thread covers (h, 4 d's, 16 e's, 16 nn's)
#pragma unroll
        for (int gg = 0; gg < 4; ++gg) {
            int g = nnq*4 + gg;
            float4 ek[4];
#pragma unroll
            for (int dd = 0; dd < 4; ++dd) {
                int row = h*32 + dq*4 + dd;
                ek[dd] = *(float4*)&sm.kvs[row*68 + (((g ^ ((row>>3)&7))) << 2)];
            }
            if (eh == 0) {
#pragma unroll
                for (int dd = 0; dd < 4; ++dd)
                    zacc[dd] += ek[dd].x + ek[dd].y + ek[dd].z + ek[dd].w;
            }
#pragma unroll
            for (int i = 0; i < 16; ++i) {
                int row = 128 + h*32 + eh*16 + i;
                float4 vv = *(float4*)&sm.kvs[row*68 + (((g ^ ((row>>3)&7))) << 2)];
#pragma unroll
                for (int dd = 0; dd < 4; ++dd)
                    cacc[dd][i] += ek[dd].x*vv.x + ek[dd].y*vv.y + ek[dd].z*vv.z + ek[dd].w*vv.w;
            }
        }
        __syncthreads();                 // kvs reads done before next tile's xns staging
    }

    // merge the 4 nn-quarter copies in LDS, then one streaming partial write per block
#pragma unroll
    for (int dd = 0; dd < 4; ++dd) {
        int base = nnq*4224 + h*1024 + (dq*4+dd)*32 + eh*16;
        *(float4*)&sm.kvs[base + 0]  = make_float4(cacc[dd][0],  cacc[dd][1],  cacc[dd][2],  cacc[dd][3]);
        *(float4*)&sm.kvs[base + 4]  = make_float4(cacc[dd][4],  cacc[dd][5],  cacc[dd][6],  cacc[dd][7]);
        *(float4*)&sm.kvs[base + 8]  = make_float4(cacc[dd][8],  cacc[dd][9],  cacc[dd][10], cacc[dd][11]);
        *(float4*)&sm.kvs[base + 12] = make_float4(cacc[dd][12], cacc[dd][13], cacc[dd][14], cacc[dd][15]);
    }
    if (eh == 0) {
#pragma unroll
        for (int dd = 0; dd < 4; ++dd)
            sm.kvs[nnq*4224 + 4096 + h*32 + dq*4 + dd] = zacc[dd];
    }
    __syncthreads();
    for (int e = tid; e < 4224; e += 256) {
        float s = sm.kvs[e] + sm.kvs[4224 + e] + sm.kvs[2*4224 + e] + sm.kvs[3*4224 + e];
        part_kv[blockIdx.x * 4224 + e] = s;
    }
}

// ---------------- reduce partials + memory-kv init -> ctx, Z ---------------------------
__global__ void reduce_ctx(const float* __restrict__ part_kv, const float* __restrict__ mem_kv,
                           float* __restrict__ ctx, float* __restrict__ Z) {
    int gid = blockIdx.x * 256 + threadIdx.x;   // 0..8447
    int b = gid / 4224;
    int e = gid - b * 4224;
    const float* p = part_kv + (size_t)b * 256 * 4224 + e;
    float s0 = 0.f, s1 = 0.f, s2 = 0.f, s3 = 0.f;
    for (int i = 0; i < 256; i += 4) {
        s0 += p[(i+0)*4224];
        s1 += p[(i+1)*4224];
        s2 += p[(i+2)*4224];
        s3 += p[(i+3)*4224];
    }
    float s = (s0 + s1) + (s2 + s3);
    if (e < 4096) {
        int hh = e >> 10, d = (e >> 5) & 31, ee = e & 31;
        float init = 0.f;
        for (int m = 0; m < 4; ++m)
            init += expf(mem_kv[hh*128 + d*4 + m]) * mem_kv[512 + hh*128 + ee*4 + m];
        ctx[b*4096 + e] = init + s;
    } else {
        int d2 = e - 4096;
        float init = 0.f;
        for (int m = 0; m < 4; ++m) init += expf(mem_kv[d2*4 + m]);
        Z[b*128 + d2] = init + s;
    }
}

// ---------------- out pass: q GEMM -> softmax(d) -> ctx apply -> w_out GEMM + gn2 part --
__global__ __launch_bounds__(256, 2) void out_pass(const float* __restrict__ x,
        const float* __restrict__ w_qkv,
        const float* __restrict__ n1w, const float* __restrict__ n1b,
        const float* __restrict__ mu, const float* __restrict__ rs,
        const float* __restrict__ ctx, const float* __restrict__ Z,
        const float* __restrict__ w_out, const float* __restrict__ b_out,
        float* __restrict__ out, float* __restrict__ part2) {
    __shared__ union { float xns[128][64]; float hid[128][64]; } ra;
    __shared__ union { float wsm[128][17]; float ctxs[4][32][32]; } rb;
    __shared__ float qs[128][64];
    int tid = threadIdx.x;
    int p0 = blockIdx.x << 6;
    int b  = p0 >> 16;
    int n0 = p0 & 65535;

#pragma unroll
    for (int it = 0; it < 8; ++it) {
        int fi = it * 256 + tid;
        int c = fi >> 4, nq = fi & 15;
        float4 v = *(const float4*)(x + ((b*CH + c) << 16) + n0 + nq*4);
        int fg = b*32 + (c >> 2);
        float aa = rs[fg] * n1w[c];
        float bb = n1b[c] - mu[fg] * aa;
        ra.xns[c][nq*4+0] = v.x*aa+bb;
        ra.xns[c][nq*4+1] = v.y*aa+bb;
        ra.xns[c][nq*4+2] = v.z*aa+bb;
        ra.xns[c][nq*4+3] = v.w*aa+bb;
    }

    float acc[4][8];
#pragma unroll
    for (int i = 0; i < 4; ++i)
#pragma unroll
        for (int j = 0; j < 8; ++j) acc[i][j] = 0.f;
    int rt = tid >> 3, nt = tid & 7;
    for (int cc = 0; cc < 128; cc += 16) {    // q GEMM: w_qkv rows 0..127
        __syncthreads();
#pragma unroll
        for (int it = 0; it < 2; ++it) {
            int fi = it * 256 + tid;
            int r = fi >> 2, cq = fi & 3;
            float4 v = *(const float4*)(w_qkv + r*CH + cc + cq*4);
            rb.wsm[r][cq*4+0] = v.x;
            rb.wsm[r][cq*4+1] = v.y;
            rb.wsm[r][cq*4+2] = v.z;
            rb.wsm[r][cq*4+3] = v.w;
        }
        __syncthreads();
#pragma unroll
        for (int k = 0; k < 16; ++k) {
            float rw[4], xv[8];
#pragma unroll
            for (int i = 0; i < 4; ++i) rw[i] = rb.wsm[rt*4+i][k];
#pragma unroll
            for (int j = 0; j < 8; ++j) xv[j] = ra.xns[cc+k][nt*8+j];
#pragma unroll
            for (int i = 0; i < 4; ++i)
#pragma unroll
                for (int j = 0; j < 8; ++j) acc[i][j] += rw[i]*xv[j];
        }
    }
    __syncthreads();
#pragma unroll
    for (int i = 0; i < 4; ++i)
#pragma unroll
        for (int j = 0; j < 8; ++j) qs[rt*4+i][nt*8+j] = acc[i][j];
    for (int idx = tid; idx < 4096; idx += 256) {
        int e = idx & 31, dd = (idx >> 5) & 31, h2 = idx >> 10;
        rb.ctxs[h2][dd][e] = ctx[b*4096 + idx] / Z[b*128 + h2*32 + dd];
    }
    __syncthreads();

    {   // softmax over d per (h,n) column
        int h2 = tid >> 6, n = tid & 63;
        float pv[32]; float ssum = 0.f;
#pragma unroll
        for (int dd = 0; dd < 32; ++dd) { pv[dd] = expf(qs[h2*32+dd][n]); ssum += pv[dd]; }
        float inv = SCALE / ssum;
#pragma unroll
        for (int dd = 0; dd < 32; ++dd) qs[h2*32+dd][n] = pv[dd] * inv;
    }
    __syncthreads();

    {   // hid[e][n] = sum_d ctx[d][e] * qprob[d][n]   (per head)
        int h2 = tid >> 6, l = tid & 63;
        int et = l >> 3, nt2 = l & 7;
        float a3[4][8];
#pragma unroll
        for (int i = 0; i < 4; ++i)
#pragma unroll
            for (int j = 0; j < 8; ++j) a3[i][j] = 0.f;
#pragma unroll
        for (int dd = 0; dd < 32; ++dd) {
            float4 cv = *(const float4*)&rb.ctxs[h2][dd][et*4];
            float rw[4] = {cv.x, cv.y, cv.z, cv.w};
            float xv[8];
#pragma unroll
            for (int j = 0; j < 8; ++j) xv[j] = qs[h2*32+dd][nt2*8+j];
#pragma unroll
            for (int i = 0; i < 4; ++i)
#pragma unroll
                for (int j = 0; j < 8; ++j) a3[i][j] += rw[i]*xv[j];
        }
#pragma unroll
        for (int i = 0; i < 4; ++i)
#pragma unroll
            for (int j = 0; j < 8; ++j) ra.hid[h2*32 + et*4 + i][nt2*8 + j] = a3[i][j];
    }

    float a2[4][8];
#pragma unroll
    for (int i = 0; i < 4; ++i)
#pragma unroll
        for (int j = 0; j < 8; ++j) a2[i][j] = 0.f;
    for (int cc = 0; cc < 128; cc += 16) {     // final GEMM: w_out @ hid
        __syncthreads();
#pragma unroll
        for (int it = 0; it < 2; ++it) {
            int fi = it * 256 + tid;
            int r = fi >> 2, cq = fi & 3;
            float4 v = *(const float4*)(w_out + r*CH + cc + cq*4);
            rb.wsm[r][cq*4+0] = v.x;
            rb.wsm[r][cq*4+1] = v.y;
            rb.wsm[r][cq*4+2] = v.z;
            rb.wsm[r][cq*4+3] = v.w;
        }
        __syncthreads();
#pragma unroll
        for (int k = 0; k < 16; ++k) {
            float rw[4], hv[8];
#pragma unroll
            for (int i = 0; i < 4; ++i) rw[i] = rb.wsm[rt*4+i][k];
#pragma unroll
            for (int j = 0; j < 8; ++j) hv[j] = ra.hid[cc+k][nt*8+j];
#pragma unroll
            for (int i = 0; i < 4; ++i)
#pragma unroll
                for (int j = 0; j < 8; ++j) a2[i][j] += rw[i]*hv[j];
        }
    }

    float gs = 0.f, gq = 0.f;
#pragma unroll
    for (int i = 0; i < 4; ++i) {
        int c = rt*4 + i;
        float bo = b_out[c];
        float o[8];
#pragma unroll
        for (int j = 0; j < 8; ++j) { o[j] = a2[i][j] + bo; gs += o[j]; gq += o[j]*o[j]; }
        float* dst = out + ((b*CH + c) << 16) + n0 + nt*8;
        *(float4*)dst       = make_float4(o[0], o[1], o[2], o[3]);
        *(float4*)(dst + 4) = make_float4(o[4], o[5], o[6], o[7]);
    }
    // gn2 partial: reduce over the 8 nt threads of each rt (group = rt)
    float2* rbuf = (float2*)&qs[0][0];
    rbuf[rt*8 + nt] = make_float2(gs, gq);
    __syncthreads();
    if (tid < 32) {
        float ss = 0.f, qq = 0.f;
#pragma unroll
        for (int k2 = 0; k2 < 8; ++k2) { float2 v = rbuf[tid*8 + k2]; ss += v.x; qq += v.y; }
        part2[blockIdx.x*64 + tid*2 + 0] = ss;
        part2[blockIdx.x*64 + tid*2 + 1] = qq;
    }
}

// ---------------- gn2 finalize --------------------------------------------------------
__global__ __launch_bounds__(256) void reduce2(const float* __restrict__ part2,
                                               float* __restrict__ mu, float* __restrict__ rs) {
    __shared__ float s1[256], s2[256];
    int fg = blockIdx.x;          // 0..63
    int b = fg >> 5, g = fg & 31;
    int t = threadIdx.x;
    float s = 0.f, q = 0.f;
    for (int i = t; i < 1024; i += 256) {
        const float* p = part2 + (size_t)(b*1024 + i)*64 + g*2;
        s += p[0]; q += p[1];
    }
    s1[t] = s; s2[t] = q;
    __syncthreads();
    for (int st = 128; st > 0; st >>= 1) {
        if (t < st) { s1[t] += s1[t + st]; s2[t] += s2[t + st]; }
        __syncthreads();
    }
    if (t == 0) {
        float m = s1[0] * (1.f / GSIZE);
        float v = s2[0] * (1.f / GSIZE) - m*m;
        mu[fg] = m; rs[fg] = rsqrtf(v + EPSV);
    }
}

__global__ __launch_bounds__(256) void gn_apply(float* __restrict__ y,
        const float* __restrict__ mu, const float* __restrict__ rs,
        const float* __restrict__ w2, const float* __restrict__ b2) {
    int bi = blockIdx.x, t = threadIdx.x;
    int c = (bi >> 3) & 127;
    int b = bi >> 10;
    int fg = b*32 + (c >> 2);
    float aa = rs[fg] * w2[c];
    float bb = b2[c] - mu[fg] * aa;
    float4* yp = (float4*)(y + (size_t)bi * 8192);
#pragma unroll
    for (int i = 0; i < 8; ++i) {
        float4 v = yp[t + 256*i];
        v.x = v.x*aa+bb; v.y = v.y*aa+bb; v.z = v.z*aa+bb; v.w = v.w*aa+bb;
        yp[t + 256*i] = v;
    }
}

extern "C" void kernel_launch(void* const* d_in, const int* in_sizes, int n_in,
                              void* d_out, int out_size, void* d_ws, size_t ws_size,
                              hipStream_t stream) {
    (void)in_sizes; (void)n_in; (void)out_size; (void)ws_size;
    const float* x      = (const float*)d_in[0];
    const float* n1w    = (const float*)d_in[1];
    const float* n1b    = (const float*)d_in[2];
    const float* w_qkv  = (const float*)d_in[3];
    const float* mem_kv = (const float*)d_in[4];
    const float* w_out  = (const float*)d_in[5];
    const float* b_out  = (const float*)d_in[6];
    const float* n2w    = (const float*)d_in[7];
    const float* n2b    = (const float*)d_in[8];
    float* out = (float*)d_out;
    float* ws  = (float*)d_ws;

    float* part1   = ws;              // 4096
    float* mu1     = ws + 4096;       // 64
    float* rs1     = ws + 4160;       // 64
    float* ctx     = ws + 4224;       // 8192
    float* Z       = ws + 12416;      // 256
    float* part2   = ws + 12672;      // 2048*64 = 131072
    float* mu2     = ws + 143744;     // 64
    float* rs2     = ws + 143808;     // 64
    float* part_kv = ws + 143872;     // 512*4224 = 2162688  (total ~9.2 MB)

    gn_partial<<<2048, 256, 0, stream>>>(x, part1);
    prep1<<<1, 64, 0, stream>>>(part1, mu1, rs1);
    kv_pass<<<512, 256, 0, stream>>>(x, w_qkv, n1w, n1b, mu1, rs1, part_kv);
    reduce_ctx<<<33, 256, 0, stream>>>(part_kv, mem_kv, ctx, Z);
    out_pass<<<2048, 256, 0, stream>>>(x, w_qkv, n1w, n1b, mu1, rs1, ctx, Z, w_out, b_out, out, part2);
    reduce2<<<64, 256, 0, stream>>>(part2, mu2, rs2);
    gn_apply<<<2048, 256, 0, stream>>>(out, mu2, rs2, n2w, n2b);
}

// Round 3
// 524.813 us; speedup vs baseline: 2.1746x; 1.1419x over previous
//
#include <hip/hip_runtime.h>
#include <math.h>

#define CH     128
#define EPSV   1e-5f
#define SCALE  0.17677669529663687f   // 32^-0.5
#define GSIZE  262144.0f

// ---------------- group-norm partial stats (2048 blocks x 8192 elems) ----------------
__global__ __launch_bounds__(256) void gn_partial(const float* __restrict__ x,
                                                  float* __restrict__ part) {
    __shared__ float s1[256], s2[256];
    int t = threadIdx.x;
    const float4* xp = (const float4*)(x + (size_t)blockIdx.x * 8192);
    float s = 0.f, q = 0.f;
#pragma unroll
    for (int i = 0; i < 8; ++i) {
        float4 v = xp[t + 256 * i];
        s += v.x + v.y + v.z + v.w;
        q += v.x * v.x + v.y * v.y + v.z * v.z + v.w * v.w;
    }
    s1[t] = s; s2[t] = q;
    __syncthreads();
    for (int st = 128; st > 0; st >>= 1) {
        if (t < st) { s1[t] += s1[t + st]; s2[t] += s2[t + st]; }
        __syncthreads();
    }
    if (t == 0) { part[2 * blockIdx.x] = s1[0]; part[2 * blockIdx.x + 1] = s2[0]; }
}

// ---------------- finalize gn1 stats ---------------------------------------------------
__global__ void prep1(const float* __restrict__ part, float* __restrict__ mu, float* __restrict__ rs) {
    int t = threadIdx.x;   // 64 threads
    float s = 0.f, q = 0.f;
    for (int i = 0; i < 32; ++i) { s += part[2*(t*32+i)]; q += part[2*(t*32+i)+1]; }
    float m = s * (1.f / GSIZE);
    float v = q * (1.f / GSIZE) - m * m;
    mu[t] = m; rs[t] = rsqrtf(v + EPSV);
}

// ---------------- k/v pass: per-block partial ctx/Z, no atomics, spill-free ------------
// grid 512; block bi handles tiles bi*4 .. bi*4+3 (64 positions each), all in batch bi>>8.
__global__ __launch_bounds__(256, 2) void kv_pass(const float* __restrict__ x,
        const float* __restrict__ w_qkv,
        const float* __restrict__ n1w, const float* __restrict__ n1b,
        const float* __restrict__ mu, const float* __restrict__ rs,
        float* __restrict__ part_kv) {
    __shared__ union {
        struct { float xns[128][68]; float wsmT[16][260]; } a;
        float kvs[17408];          // [256 rows][68], 4-float granules XOR-swizzled by (row>>3)&7
    } sm;
    int tid = threadIdx.x;
    int rt = tid >> 3, nt = tid & 7;                 // GEMM micro-tile coords
    int h = tid >> 6, l = tid & 63;                  // ctx-phase coords
    int d = l >> 1, eh = l & 1;
    int krow = h*32 + d, swk = (krow >> 3) & 7;

    float cacc[16];
    float zacc = 0.f;
#pragma unroll
    for (int e = 0; e < 16; ++e) cacc[e] = 0.f;

    int b = blockIdx.x >> 8;

    for (int t4 = 0; t4 < 4; ++t4) {
        int n0 = ((blockIdx.x * 4 + t4) << 6) & 65535;

        // stage + normalize x tile (128 ch x 64 pos)
#pragma unroll
        for (int it = 0; it < 8; ++it) {
            int fi = it * 256 + tid;
            int c = fi >> 4, nq = fi & 15;
            float4 v = *(const float4*)(x + ((b*CH + c) << 16) + n0 + nq*4);
            int fg = b*32 + (c >> 2);
            float aa = rs[fg] * n1w[c];
            float bb = n1b[c] - mu[fg] * aa;
            *(float4*)&sm.a.xns[c][nq*4] =
                make_float4(v.x*aa+bb, v.y*aa+bb, v.z*aa+bb, v.w*aa+bb);
        }

        float acc[8][8];
#pragma unroll
        for (int i = 0; i < 8; ++i)
#pragma unroll
            for (int j = 0; j < 8; ++j) acc[i][j] = 0.f;

        for (int cc = 0; cc < 128; cc += 16) {
            __syncthreads();
#pragma unroll
            for (int it = 0; it < 4; ++it) {         // stage w_qkv rows 128..383, 16 cols, transposed
                int fi = it * 256 + tid;
                int r = fi >> 2, cq = fi & 3;
                float4 v = *(const float4*)(w_qkv + (128 + r)*CH + cc + cq*4);
                sm.a.wsmT[cq*4+0][r] = v.x;
                sm.a.wsmT[cq*4+1][r] = v.y;
                sm.a.wsmT[cq*4+2][r] = v.z;
                sm.a.wsmT[cq*4+3][r] = v.w;
            }
            __syncthreads();
#pragma unroll
            for (int k = 0; k < 16; ++k) {
                float4 w0 = *(float4*)&sm.a.wsmT[k][rt*8];
                float4 w1 = *(float4*)&sm.a.wsmT[k][rt*8+4];
                float4 x0 = *(float4*)&sm.a.xns[cc+k][nt*8];
                float4 x1 = *(float4*)&sm.a.xns[cc+k][nt*8+4];
                float rw[8] = {w0.x,w0.y,w0.z,w0.w,w1.x,w1.y,w1.z,w1.w};
                float xv[8] = {x0.x,x0.y,x0.z,x0.w,x1.x,x1.y,x1.z,x1.w};
#pragma unroll
                for (int i = 0; i < 8; ++i)
#pragma unroll
                    for (int j = 0; j < 8; ++j) acc[i][j] += rw[i]*xv[j];
            }
        }
        __syncthreads();                 // GEMM LDS reads done before union overwrite

        // write exp(k)/v into kvs (row-major, granule-swizzled)
        int sw = rt & 7;
#pragma unroll
        for (int i = 0; i < 8; ++i) {
            int row = rt*8 + i;
            float4 lo, hi;
            if (row < 128) {
                lo = make_float4(expf(acc[i][0]), expf(acc[i][1]), expf(acc[i][2]), expf(acc[i][3]));
                hi = make_float4(expf(acc[i][4]), expf(acc[i][5]), expf(acc[i][6]), expf(acc[i][7]));
            } else {
                lo = make_float4(acc[i][0], acc[i][1], acc[i][2], acc[i][3]);
                hi = make_float4(acc[i][4], acc[i][5], acc[i][6], acc[i][7]);
            }
            int g0 = (2*nt) ^ sw, g1 = (2*nt + 1) ^ sw;
            *(float4*)&sm.kvs[row*68 + g0*4] = lo;
            *(float4*)&sm.kvs[row*68 + g1*4] = hi;
        }
        __syncthreads();

        // ctx accumulate: thread = (h, d, eh) over all 64 nn of this tile
#pragma unroll
        for (int g = 0; g < 16; ++g) {
            float4 ek = *(float4*)&sm.kvs[krow*68 + ((g ^ swk) << 2)];
            zacc += ek.x + ek.y + ek.z + ek.w;
#pragma unroll
            for (int i = 0; i < 16; ++i) {
                int vrow = 128 + h*32 + eh*16 + i;
                float4 vv = *(float4*)&sm.kvs[vrow*68 + ((g ^ ((vrow>>3)&7)) << 2)];
                cacc[i] += ek.x*vv.x + ek.y*vv.y + ek.z*vv.z + ek.w*vv.w;
            }
        }
        __syncthreads();                 // kvs reads done before next tile's xns staging
    }

    // direct streaming partial write (single copy per thread, no merge needed)
    float* dst = part_kv + (size_t)blockIdx.x * 4224 + h*1024 + d*32 + eh*16;
    *(float4*)&dst[0]  = make_float4(cacc[0],  cacc[1],  cacc[2],  cacc[3]);
    *(float4*)&dst[4]  = make_float4(cacc[4],  cacc[5],  cacc[6],  cacc[7]);
    *(float4*)&dst[8]  = make_float4(cacc[8],  cacc[9],  cacc[10], cacc[11]);
    *(float4*)&dst[12] = make_float4(cacc[12], cacc[13], cacc[14], cacc[15]);
    if (eh == 0) part_kv[(size_t)blockIdx.x * 4224 + 4096 + krow] = zacc;
}

// ---------------- reduce partials + memory-kv init -> ctx, Z ---------------------------
__global__ void reduce_ctx(const float* __restrict__ part_kv, const float* __restrict__ mem_kv,
                           float* __restrict__ ctx, float* __restrict__ Z) {
    int gid = blockIdx.x * 256 + threadIdx.x;   // 0..8447
    int b = gid / 4224;
    int e = gid - b * 4224;
    const float* p = part_kv + (size_t)b * 256 * 4224 + e;
    float s0 = 0.f, s1 = 0.f, s2 = 0.f, s3 = 0.f;
    for (int i = 0; i < 256; i += 4) {
        s0 += p[(i+0)*4224];
        s1 += p[(i+1)*4224];
        s2 += p[(i+2)*4224];
        s3 += p[(i+3)*4224];
    }
    float s = (s0 + s1) + (s2 + s3);
    if (e < 4096) {
        int hh = e >> 10, d = (e >> 5) & 31, ee = e & 31;
        float init = 0.f;
        for (int m = 0; m < 4; ++m)
            init += expf(mem_kv[hh*128 + d*4 + m]) * mem_kv[512 + hh*128 + ee*4 + m];
        ctx[b*4096 + e] = init + s;
    } else {
        int d2 = e - 4096;
        float init = 0.f;
        for (int m = 0; m < 4; ++m) init += expf(mem_kv[d2*4 + m]);
        Z[b*128 + d2] = init + s;
    }
}

// ---------------- out pass: q GEMM -> softmax(d) -> ctx apply -> w_out GEMM + gn2 part --
__global__ __launch_bounds__(256, 2) void out_pass(const float* __restrict__ x,
        const float* __restrict__ w_qkv,
        const float* __restrict__ n1w, const float* __restrict__ n1b,
        const float* __restrict__ mu, const float* __restrict__ rs,
        const float* __restrict__ ctx, const float* __restrict__ Z,
        const float* __restrict__ w_out, const float* __restrict__ b_out,
        float* __restrict__ out, float* __restrict__ part2) {
    __shared__ union { float xns[128][64]; float hid[128][64]; } ra;
    __shared__ union { float wsm[128][17]; float ctxs[4][32][32]; } rb;
    __shared__ float qs[128][64];
    int tid = threadIdx.x;
    int p0 = blockIdx.x << 6;
    int b  = p0 >> 16;
    int n0 = p0 & 65535;

#pragma unroll
    for (int it = 0; it < 8; ++it) {
        int fi = it * 256 + tid;
        int c = fi >> 4, nq = fi & 15;
        float4 v = *(const float4*)(x + ((b*CH + c) << 16) + n0 + nq*4);
        int fg = b*32 + (c >> 2);
        float aa = rs[fg] * n1w[c];
        float bb = n1b[c] - mu[fg] * aa;
        ra.xns[c][nq*4+0] = v.x*aa+bb;
        ra.xns[c][nq*4+1] = v.y*aa+bb;
        ra.xns[c][nq*4+2] = v.z*aa+bb;
        ra.xns[c][nq*4+3] = v.w*aa+bb;
    }

    float acc[4][8];
#pragma unroll
    for (int i = 0; i < 4; ++i)
#pragma unroll
        for (int j = 0; j < 8; ++j) acc[i][j] = 0.f;
    int rt = tid >> 3, nt = tid & 7;
    for (int cc = 0; cc < 128; cc += 16) {    // q GEMM: w_qkv rows 0..127
        __syncthreads();
#pragma unroll
        for (int it = 0; it < 2; ++it) {
            int fi = it * 256 + tid;
            int r = fi >> 2, cq = fi & 3;
            float4 v = *(const float4*)(w_qkv + r*CH + cc + cq*4);
            rb.wsm[r][cq*4+0] = v.x;
            rb.wsm[r][cq*4+1] = v.y;
            rb.wsm[r][cq*4+2] = v.z;
            rb.wsm[r][cq*4+3] = v.w;
        }
        __syncthreads();
#pragma unroll
        for (int k = 0; k < 16; ++k) {
            float rw[4], xv[8];
#pragma unroll
            for (int i = 0; i < 4; ++i) rw[i] = rb.wsm[rt*4+i][k];
#pragma unroll
            for (int j = 0; j < 8; ++j) xv[j] = ra.xns[cc+k][nt*8+j];
#pragma unroll
            for (int i = 0; i < 4; ++i)
#pragma unroll
                for (int j = 0; j < 8; ++j) acc[i][j] += rw[i]*xv[j];
        }
    }
    __syncthreads();
#pragma unroll
    for (int i = 0; i < 4; ++i)
#pragma unroll
        for (int j = 0; j < 8; ++j) qs[rt*4+i][nt*8+j] = acc[i][j];
    for (int idx = tid; idx < 4096; idx += 256) {
        int e = idx & 31, dd = (idx >> 5) & 31, h2 = idx >> 10;
        rb.ctxs[h2][dd][e] = ctx[b*4096 + idx] / Z[b*128 + h2*32 + dd];
    }
    __syncthreads();

    {   // softmax over d per (h,n) column
        int h2 = tid >> 6, n = tid & 63;
        float pv[32]; float ssum = 0.f;
#pragma unroll
        for (int dd = 0; dd < 32; ++dd) { pv[dd] = expf(qs[h2*32+dd][n]); ssum += pv[dd]; }
        float inv = SCALE / ssum;
#pragma unroll
        for (int dd = 0; dd < 32; ++dd) qs[h2*32+dd][n] = pv[dd] * inv;
    }
    __syncthreads();

    {   // hid[e][n] = sum_d ctx[d][e] * qprob[d][n]   (per head)
        int h2 = tid >> 6, l = tid & 63;
        int et = l >> 3, nt2 = l & 7;
        float a3[4][8];
#pragma unroll
        for (int i = 0; i < 4; ++i)
#pragma unroll
            for (int j = 0; j < 8; ++j) a3[i][j] = 0.f;
#pragma unroll
        for (int dd = 0; dd < 32; ++dd) {
            float4 cv = *(const float4*)&rb.ctxs[h2][dd][et*4];
            float rw[4] = {cv.x, cv.y, cv.z, cv.w};
            float xv[8];
#pragma unroll
            for (int j = 0; j < 8; ++j) xv[j] = qs[h2*32+dd][nt2*8+j];
#pragma unroll
            for (int i = 0; i < 4; ++i)
#pragma unroll
                for (int j = 0; j < 8; ++j) a3[i][j] += rw[i]*xv[j];
        }
#pragma unroll
        for (int i = 0; i < 4; ++i)
#pragma unroll
            for (int j = 0; j < 8; ++j) ra.hid[h2*32 + et*4 + i][nt2*8 + j] = a3[i][j];
    }

    float a2[4][8];
#pragma unroll
    for (int i = 0; i < 4; ++i)
#pragma unroll
        for (int j = 0; j < 8; ++j) a2[i][j] = 0.f;
    for (int cc = 0; cc < 128; cc += 16) {     // final GEMM: w_out @ hid
        __syncthreads();
#pragma unroll
        for (int it = 0; it < 2; ++it) {
            int fi = it * 256 + tid;
            int r = fi >> 2, cq = fi & 3;
            float4 v = *(const float4*)(w_out + r*CH + cc + cq*4);
            rb.wsm[r][cq*4+0] = v.x;
            rb.wsm[r][cq*4+1] = v.y;
            rb.wsm[r][cq*4+2] = v.z;
            rb.wsm[r][cq*4+3] = v.w;
        }
        __syncthreads();
#pragma unroll
        for (int k = 0; k < 16; ++k) {
            float rw[4], hv[8];
#pragma unroll
            for (int i = 0; i < 4; ++i) rw[i] = rb.wsm[rt*4+i][k];
#pragma unroll
            for (int j = 0; j < 8; ++j) hv[j] = ra.hid[cc+k][nt*8+j];
#pragma unroll
            for (int i = 0; i < 4; ++i)
#pragma unroll
                for (int j = 0; j < 8; ++j) a2[i][j] += rw[i]*hv[j];
        }
    }

    float gs = 0.f, gq = 0.f;
#pragma unroll
    for (int i = 0; i < 4; ++i) {
        int c = rt*4 + i;
        float bo = b_out[c];
        float o[8];
#pragma unroll
        for (int j = 0; j < 8; ++j) { o[j] = a2[i][j] + bo; gs += o[j]; gq += o[j]*o[j]; }
        float* dst = out + ((b*CH + c) << 16) + n0 + nt*8;
        *(float4*)dst       = make_float4(o[0], o[1], o[2], o[3]);
        *(float4*)(dst + 4) = make_float4(o[4], o[5], o[6], o[7]);
    }
    // gn2 partial: reduce over the 8 nt threads of each rt (group = rt)
    float2* rbuf = (float2*)&qs[0][0];
    rbuf[rt*8 + nt] = make_float2(gs, gq);
    __syncthreads();
    if (tid < 32) {
        float ss = 0.f, qq = 0.f;
#pragma unroll
        for (int k2 = 0; k2 < 8; ++k2) { float2 v = rbuf[tid*8 + k2]; ss += v.x; qq += v.y; }
        part2[blockIdx.x*64 + tid*2 + 0] = ss;
        part2[blockIdx.x*64 + tid*2 + 1] = qq;
    }
}

// ---------------- gn2 finalize --------------------------------------------------------
__global__ __launch_bounds__(256) void reduce2(const float* __restrict__ part2,
                                               float* __restrict__ mu, float* __restrict__ rs) {
    __shared__ float s1[256], s2[256];
    int fg = blockIdx.x;          // 0..63
    int b = fg >> 5, g = fg & 31;
    int t = threadIdx.x;
    float s = 0.f, q = 0.f;
    for (int i = t; i < 1024; i += 256) {
        const float* p = part2 + (size_t)(b*1024 + i)*64 + g*2;
        s += p[0]; q += p[1];
    }
    s1[t] = s; s2[t] = q;
    __syncthreads();
    for (int st = 128; st > 0; st >>= 1) {
        if (t < st) { s1[t] += s1[t + st]; s2[t] += s2[t + st]; }
        __syncthreads();
    }
    if (t == 0) {
        float m = s1[0] * (1.f / GSIZE);
        float v = s2[0] * (1.f / GSIZE) - m*m;
        mu[fg] = m; rs[fg] = rsqrtf(v + EPSV);
    }
}

__global__ __launch_bounds__(256) void gn_apply(float* __restrict__ y,
        const float* __restrict__ mu, const float* __restrict__ rs,
        const float* __restrict__ w2, const float* __restrict__ b2) {
    int bi = blockIdx.x, t = threadIdx.x;
    int c = (bi >> 3) & 127;
    int b = bi >> 10;
    int fg = b*32 + (c >> 2);
    float aa = rs[fg] * w2[c];
    float bb = b2[c] - mu[fg] * aa;
    float4* yp = (float4*)(y + (size_t)bi * 8192);
#pragma unroll
    for (int i = 0; i < 8; ++i) {
        float4 v = yp[t + 256*i];
        v.x = v.x*aa+bb; v.y = v.y*aa+bb; v.z = v.z*aa+bb; v.w = v.w*aa+bb;
        yp[t + 256*i] = v;
    }
}

extern "C" void kernel_launch(void* const* d_in, const int* in_sizes, int n_in,
                              void* d_out, int out_size, void* d_ws, size_t ws_size,
                              hipStream_t stream) {
    (void)in_sizes; (void)n_in; (void)out_size; (void)ws_size;
    const float* x      = (const float*)d_in[0];
    const float* n1w    = (const float*)d_in[1];
    const float* n1b    = (const float*)d_in[2];
    const float* w_qkv  = (const float*)d_in[3];
    const float* mem_kv = (const float*)d_in[4];
    const float* w_out  = (const float*)d_in[5];
    const float* b_out  = (const float*)d_in[6];
    const float* n2w    = (const float*)d_in[7];
    const float* n2b    = (const float*)d_in[8];
    float* out = (float*)d_out;
    float* ws  = (float*)d_ws;

    float* part1   = ws;              // 4096
    float* mu1     = ws + 4096;       // 64
    float* rs1     = ws + 4160;       // 64
    float* ctx     = ws + 4224;       // 8192
    float* Z       = ws + 12416;      // 256
    float* part2   = ws + 12672;      // 2048*64 = 131072
    float* mu2     = ws + 143744;     // 64
    float* rs2     = ws + 143808;     // 64
    float* part_kv = ws + 143872;     // 512*4224 = 2162688  (total ~9.2 MB)

    gn_partial<<<2048, 256, 0, stream>>>(x, part1);
    prep1<<<1, 64, 0, stream>>>(part1, mu1, rs1);
    kv_pass<<<512, 256, 0, stream>>>(x, w_qkv, n1w, n1b, mu1, rs1, part_kv);
    reduce_ctx<<<33, 256, 0, stream>>>(part_kv, mem_kv, ctx, Z);
    out_pass<<<2048, 256, 0, stream>>>(x, w_qkv, n1w, n1b, mu1, rs1, ctx, Z, w_out, b_out, out, part2);
    reduce2<<<64, 256, 0, stream>>>(part2, mu2, rs2);
    gn_apply<<<2048, 256, 0, stream>>>(out, mu2, rs2, n2w, n2b);
}